// Round 2
// baseline (87.836 us; speedup 1.0000x reference)
//
#include <hip/hip_runtime.h>

#define NNZ   104858
#define NB    1024   // batch
#define NIN   1024   // in_features
#define NOUT  1024   // out_features
#define CHUNK 256

// ---------------- CSR build ----------------

__global__ void k_hist_init(int* __restrict__ row_count) {
    row_count[threadIdx.x] = 0;  // 1 block x 1024
}

__global__ void k_hist(const int* __restrict__ idx, int* __restrict__ row_count) {
    int k = blockIdx.x * 256 + threadIdx.x;
    if (k < NNZ) atomicAdd(&row_count[idx[k] & (NOUT - 1)], 1);
}

// 1 block x 1024 threads: exclusive scan of row_count -> row_start[1025], cursor copy
__global__ void k_scan(const int* __restrict__ row_count,
                       int* __restrict__ row_start, int* __restrict__ cursor) {
    __shared__ int s[1024];
    int t = threadIdx.x;
    int v = row_count[t];
    s[t] = v;
    __syncthreads();
    for (int off = 1; off < 1024; off <<= 1) {
        int add = (t >= off) ? s[t - off] : 0;
        __syncthreads();
        s[t] += add;
        __syncthreads();
    }
    int incl = s[t];
    int excl = incl - v;
    row_start[t] = excl;
    cursor[t]    = excl;
    if (t == 1023) row_start[1024] = incl;  // == NNZ
}

__global__ void k_scatter(const int* __restrict__ idx,
                          const float* __restrict__ w,
                          int* __restrict__ cursor,
                          int* __restrict__ csr_col, float* __restrict__ csr_w) {
    int k = blockIdx.x * 256 + threadIdx.x;
    if (k < NNZ) {
        int r = idx[k] & (NOUT - 1);
        int c = idx[NNZ + k] & (NIN - 1);
        int pos = atomicAdd(&cursor[r], 1);
        csr_col[pos] = c;
        csr_w[pos]   = w[k];
    }
}

// ---------------- transpose (1024x1024 f32): out[c*1024+r] = in[r*1024+c] ----
__global__ void k_transpose(const float* __restrict__ in, float* __restrict__ out) {
    __shared__ float tile[32][33];
    int tx = threadIdx.x, ty = threadIdx.y;           // block (32,8)
    int bc = blockIdx.x * 32, br = blockIdx.y * 32;   // col-base, row-base
    #pragma unroll
    for (int i = 0; i < 32; i += 8)
        tile[ty + i][tx] = in[(br + ty + i) * 1024 + bc + tx];
    __syncthreads();
    #pragma unroll
    for (int i = 0; i < 32; i += 8)
        out[(bc + ty + i) * 1024 + br + tx] = tile[tx][ty + i];
}

// ---------------- main compute: one block per output row ----------------
// xT4: x transposed, [NIN][NB] f32 viewed as float4 (NB/4 = 256 per row)
// each of 256 threads owns 4 consecutive batch elements
__global__ __launch_bounds__(256)
void k_compute(const float4* __restrict__ xT4,
               const int* __restrict__ row_start,
               const int* __restrict__ csr_col, const float* __restrict__ csr_w,
               const float* __restrict__ bias,
               float4* __restrict__ outT4) {
    __shared__ int   s_col[CHUNK];
    __shared__ float s_w[CHUNK];
    const int r = blockIdx.x;
    const int t = threadIdx.x;
    const int beg = row_start[r];
    const int end = row_start[r + 1];
    const float b = bias[r];
    float4 acc = {b, b, b, b};
    for (int j0 = beg; j0 < end; j0 += CHUNK) {
        int cnt = min(CHUNK, end - j0);
        if (t < cnt) {
            s_col[t] = csr_col[j0 + t];
            s_w[t]   = csr_w[j0 + t];
        }
        __syncthreads();
        for (int i = 0; i < cnt; ++i) {
            float  w  = s_w[i];
            float4 xv = xT4[s_col[i] * 256 + t];
            acc.x += w * xv.x;
            acc.y += w * xv.y;
            acc.z += w * xv.z;
            acc.w += w * xv.w;
        }
        __syncthreads();
    }
    outT4[r * 256 + t] = acc;  // outT[r][4t..4t+3], coalesced
}

// ---------------- launch ----------------

static inline size_t align256(size_t x) { return (x + 255) & ~(size_t)255; }

extern "C" void kernel_launch(void* const* d_in, const int* in_sizes, int n_in,
                              void* d_out, int out_size, void* d_ws, size_t ws_size,
                              hipStream_t stream) {
    const float* x    = (const float*)d_in[0];   // [NB][NIN]
    const float* wts  = (const float*)d_in[1];   // [NNZ]
    const float* bias = (const float*)d_in[2];   // [NOUT]
    const int*   idx  = (const int*)d_in[3];     // [2][NNZ] int32 (JAX x64 disabled)

    // workspace layout (~9.7 MB)
    char* ws = (char*)d_ws;
    size_t off = 0;
    float* xT       = (float*)(ws + off); off = align256(off + (size_t)NIN * NB * 4);
    float* outT     = (float*)(ws + off); off = align256(off + (size_t)NOUT * NB * 4);
    float* csr_w    = (float*)(ws + off); off = align256(off + (size_t)NNZ * 4);
    int*   csr_col  = (int*)  (ws + off); off = align256(off + (size_t)NNZ * 4);
    int*   row_cnt  = (int*)  (ws + off); off = align256(off + 1024 * 4);
    int*   row_start= (int*)  (ws + off); off = align256(off + 1025 * 4);
    int*   cursor   = (int*)  (ws + off); off = align256(off + 1024 * 4);

    const int nb_nnz = (NNZ + 255) / 256;

    k_hist_init<<<1, 1024, 0, stream>>>(row_cnt);
    k_hist<<<nb_nnz, 256, 0, stream>>>(idx, row_cnt);
    k_scan<<<1, 1024, 0, stream>>>(row_cnt, row_start, cursor);
    k_scatter<<<nb_nnz, 256, 0, stream>>>(idx, wts, cursor, csr_col, csr_w);
    k_transpose<<<dim3(32, 32), dim3(32, 8), 0, stream>>>(x, xT);
    k_compute<<<NOUT, 256, 0, stream>>>((const float4*)xT, row_start, csr_col, csr_w,
                                        bias, (float4*)outT);
    k_transpose<<<dim3(32, 32), dim3(32, 8), 0, stream>>>(outT, (float*)d_out);
}

// Round 3
// 80.289 us; speedup vs baseline: 1.0940x; 1.0940x over previous
//
#include <hip/hip_runtime.h>
#include <hip/hip_bf16.h>

#define NNZ   104858
#define NB    1024   // batch
#define NIN   1024   // in_features
#define NOUT  1024   // out_features
#define CHUNK 256

__device__ __forceinline__ float bf2f(unsigned short u) {
    union { unsigned int i; float f; } v;
    v.i = ((unsigned int)u) << 16;
    return v.f;
}

// ---------------- fused: x transpose->bf16 (blocks 0..1023) + row histogram (rest) ----
// transpose: xT_bf16[c][n] = bf16(x[n][c]);  hist: row_count[row[k]]++
__global__ __launch_bounds__(256)
void k_hist_xpose(const float* __restrict__ x, const int* __restrict__ idx,
                  unsigned short* __restrict__ xTb, int* __restrict__ row_count) {
    const int b = blockIdx.x;
    const int t = threadIdx.x;
    if (b < 1024) {
        // 32x32 transpose tile; grid-x encodes (bc, br)
        __shared__ float tile[32][33];
        const int tx = t & 31, ty = t >> 5;            // ty in [0,8)
        const int bc = (b & 31) * 32, br = (b >> 5) * 32;
        #pragma unroll
        for (int i = 0; i < 32; i += 8)
            tile[ty + i][tx] = x[(br + ty + i) * 1024 + bc + tx];
        __syncthreads();
        #pragma unroll
        for (int i = 0; i < 32; i += 8)
            xTb[(bc + ty + i) * 1024 + br + tx] = __bfloat16_as_ushort(__float2bfloat16(tile[tx][ty + i]));
    } else {
        const int k = (b - 1024) * 256 + t;
        if (k < NNZ) atomicAdd(&row_count[idx[k] & (NOUT - 1)], 1);
    }
}

// 1 block x 1024 threads: exclusive scan of row_count -> row_start[1025], cursor copy
__global__ void k_scan(const int* __restrict__ row_count,
                       int* __restrict__ row_start, int* __restrict__ cursor) {
    __shared__ int s[1024];
    int t = threadIdx.x;
    int v = row_count[t];
    s[t] = v;
    __syncthreads();
    for (int off = 1; off < 1024; off <<= 1) {
        int add = (t >= off) ? s[t - off] : 0;
        __syncthreads();
        s[t] += add;
        __syncthreads();
    }
    int incl = s[t];
    int excl = incl - v;
    row_start[t] = excl;
    cursor[t]    = excl;
    if (t == 1023) row_start[1024] = incl;  // == NNZ
}

__global__ void k_scatter(const int* __restrict__ idx,
                          const float* __restrict__ w,
                          int* __restrict__ cursor,
                          int* __restrict__ csr_col, float* __restrict__ csr_w) {
    int k = blockIdx.x * 256 + threadIdx.x;
    if (k < NNZ) {
        int r = idx[k] & (NOUT - 1);
        int c = idx[NNZ + k] & (NIN - 1);
        int pos = atomicAdd(&cursor[r], 1);
        csr_col[pos] = c;
        csr_w[pos]   = w[k];
    }
}

// ---------------- main compute: one block per output row ----------------
// xTb: x transposed bf16, [NIN][NB]; each of 256 threads owns 4 consecutive batch elems
__global__ __launch_bounds__(256)
void k_compute(const ushort4* __restrict__ xT4,   // bf16x4 per element
               const int* __restrict__ row_start,
               const int* __restrict__ csr_col, const float* __restrict__ csr_w,
               const float* __restrict__ bias,
               float4* __restrict__ outT4) {
    __shared__ int   s_col[CHUNK];
    __shared__ float s_w[CHUNK];
    const int r = blockIdx.x;
    const int t = threadIdx.x;
    const int beg = row_start[r];
    const int end = row_start[r + 1];
    const float b = bias[r];
    float4 acc = {b, b, b, b};
    for (int j0 = beg; j0 < end; j0 += CHUNK) {
        int cnt = min(CHUNK, end - j0);
        if (t < cnt) {
            s_col[t] = csr_col[j0 + t];
            s_w[t]   = csr_w[j0 + t];
        }
        __syncthreads();
        #pragma unroll 4
        for (int i = 0; i < cnt; ++i) {
            float   w  = s_w[i];
            ushort4 xv = xT4[s_col[i] * 256 + t];   // 8B/lane, contiguous per wave
            acc.x += w * bf2f(xv.x);
            acc.y += w * bf2f(xv.y);
            acc.z += w * bf2f(xv.z);
            acc.w += w * bf2f(xv.w);
        }
        __syncthreads();
    }
    outT4[r * 256 + t] = acc;  // outT[r][4t..4t+3], coalesced
}

// ---------------- final transpose (1024x1024 f32): out[n][r] = outT[r][n] ----
__global__ __launch_bounds__(256)
void k_xpose_out(const float* __restrict__ in, float* __restrict__ out) {
    __shared__ float tile[32][33];
    int t = threadIdx.x;
    int tx = t & 31, ty = t >> 5;
    int bc = blockIdx.x * 32, br = blockIdx.y * 32;
    #pragma unroll
    for (int i = 0; i < 32; i += 8)
        tile[ty + i][tx] = in[(br + ty + i) * 1024 + bc + tx];
    __syncthreads();
    #pragma unroll
    for (int i = 0; i < 32; i += 8)
        out[(bc + ty + i) * 1024 + br + tx] = tile[tx][ty + i];
}

// ---------------- launch ----------------

static inline size_t align256(size_t x) { return (x + 255) & ~(size_t)255; }

extern "C" void kernel_launch(void* const* d_in, const int* in_sizes, int n_in,
                              void* d_out, int out_size, void* d_ws, size_t ws_size,
                              hipStream_t stream) {
    const float* x    = (const float*)d_in[0];   // [NB][NIN]
    const float* wts  = (const float*)d_in[1];   // [NNZ]
    const float* bias = (const float*)d_in[2];   // [NOUT]
    const int*   idx  = (const int*)d_in[3];     // [2][NNZ] int32

    // workspace layout (~7 MB)
    char* ws = (char*)d_ws;
    size_t off = 0;
    unsigned short* xTb = (unsigned short*)(ws + off); off = align256(off + (size_t)NIN * NB * 2);
    float* outT      = (float*)(ws + off); off = align256(off + (size_t)NOUT * NB * 4);
    float* csr_w     = (float*)(ws + off); off = align256(off + (size_t)NNZ * 4);
    int*   csr_col   = (int*)  (ws + off); off = align256(off + (size_t)NNZ * 4);
    int*   row_cnt   = (int*)  (ws + off); off = align256(off + 1024 * 4);
    int*   row_start = (int*)  (ws + off); off = align256(off + 1025 * 4);
    int*   cursor    = (int*)  (ws + off); off = align256(off + 1024 * 4);

    const int nb_nnz = (NNZ + 255) / 256;

    hipMemsetAsync(row_cnt, 0, 1024 * sizeof(int), stream);
    k_hist_xpose<<<1024 + nb_nnz, 256, 0, stream>>>(x, idx, xTb, row_cnt);
    k_scan<<<1, 1024, 0, stream>>>(row_cnt, row_start, cursor);
    k_scatter<<<nb_nnz, 256, 0, stream>>>(idx, wts, cursor, csr_col, csr_w);
    k_compute<<<NOUT, 256, 0, stream>>>((const ushort4*)xTb, row_start, csr_col, csr_w,
                                        bias, (float4*)outT);
    k_xpose_out<<<dim3(32, 32), 256, 0, stream>>>(outT, (float*)d_out);
}

// Round 4
// 34.941 us; speedup vs baseline: 2.5139x; 2.2979x over previous
//
#include <hip/hip_runtime.h>
#include <hip/hip_bf16.h>

#define NNZ   104858
#define NB    1024
#define NIN   1024
#define NOUT  1024

typedef __bf16 bf16;
typedef bf16  bf16x8 __attribute__((ext_vector_type(8)));
typedef float f32x4  __attribute__((ext_vector_type(4)));

// ---------------- densify: Wd[r][c] += w_k (f32 atomics; duplicates sum) ----
__global__ __launch_bounds__(256)
void k_densify(const int* __restrict__ idx, const float* __restrict__ w,
               float* __restrict__ Wd) {
    int k = blockIdx.x * 256 + threadIdx.x;
    if (k < NNZ) {
        int r = idx[k] & (NOUT - 1);
        int c = idx[NNZ + k] & (NIN - 1);
        atomicAdd(&Wd[r * NIN + c], w[k]);
    }
}

// ---------------- fused convert: blocks 0..511 x->xb, 512..1023 Wd->Wb ------
__global__ __launch_bounds__(256)
void k_convert(const float* __restrict__ x, const float* __restrict__ Wd,
               bf16* __restrict__ xb, bf16* __restrict__ wb) {
    const int b = blockIdx.x, t = threadIdx.x;
    const float* src = (b < 512) ? x : Wd;
    bf16*        dst = (b < 512) ? xb : wb;
    const int base = ((b & 511) * 256 + t) * 8;
    const float4* s4 = (const float4*)(src + base);
    float4 v0 = s4[0], v1 = s4[1];
    bf16x8 o;
    o[0] = (bf16)v0.x; o[1] = (bf16)v0.y; o[2] = (bf16)v0.z; o[3] = (bf16)v0.w;
    o[4] = (bf16)v1.x; o[5] = (bf16)v1.y; o[6] = (bf16)v1.z; o[7] = (bf16)v1.w;
    *(bf16x8*)(dst + base) = o;
}

// ---------------- split-K GEMM: P[kz] = A[.,kz-range] * B[.,kz-range]^T -----
// A = xb [1024][1024] bf16 row-major (M=batch, K contiguous)
// B = wb [1024][1024] bf16 row-major (N=out,  K contiguous)  -> C = A*B^T
// block: 128x128 tile, 256 thr (4 waves, 2x2), BK=64, K-chunk 256 (4 steps)
__device__ __forceinline__ void gload_lds16(const void* g, void* l) {
    __builtin_amdgcn_global_load_lds((const __attribute__((address_space(1))) void*)g,
                                     (__attribute__((address_space(3))) void*)l,
                                     16, 0, 0);
}

__global__ __launch_bounds__(256)
void k_gemm(const bf16* __restrict__ A, const bf16* __restrict__ B,
            float* __restrict__ P) {
    __shared__ __align__(16) bf16 As[128 * 64];
    __shared__ __align__(16) bf16 Bs[128 * 64];
    const int t  = threadIdx.x;
    const int m0 = blockIdx.x * 128, n0 = blockIdx.y * 128, kz = blockIdx.z;
    const int lane = t & 63;
    const int wv = t >> 6, wr = wv >> 1, wc = wv & 1;
    const int fr = lane & 15, fg = lane >> 4;

    f32x4 acc[4][4] = {};

    const int srow = t >> 3;   // 0..31 within a 32-row staging issue
    const int sg   = t & 7;    // 16B granule within 128B row

    for (int ks = 0; ks < 4; ++ks) {
        const int kbase = kz * 256 + ks * 64;
        // stage A,B tiles: LDS linear dest, XOR-swizzled global source (rule #21)
        #pragma unroll
        for (int i = 0; i < 4; ++i) {
            int row = i * 32 + srow;
            int g2  = sg ^ (row & 7);             // swizzled source granule
            gload_lds16(A + (size_t)(m0 + row) * NIN + kbase + g2 * 8,
                        As + row * 64 + sg * 8);
            gload_lds16(B + (size_t)(n0 + row) * NIN + kbase + g2 * 8,
                        Bs + row * 64 + sg * 8);
        }
        __syncthreads();

        bf16x8 af[4][2], bfr[4][2];
        #pragma unroll
        for (int mi = 0; mi < 4; ++mi) {
            int row = wr * 64 + mi * 16 + fr;
            #pragma unroll
            for (int kk = 0; kk < 2; ++kk) {
                int gsw = (kk * 4 + fg) ^ (row & 7);
                af[mi][kk] = *(const bf16x8*)(As + row * 64 + gsw * 8);
            }
        }
        #pragma unroll
        for (int ni = 0; ni < 4; ++ni) {
            int row = wc * 64 + ni * 16 + fr;
            #pragma unroll
            for (int kk = 0; kk < 2; ++kk) {
                int gsw = (kk * 4 + fg) ^ (row & 7);
                bfr[ni][kk] = *(const bf16x8*)(Bs + row * 64 + gsw * 8);
            }
        }
        #pragma unroll
        for (int mi = 0; mi < 4; ++mi)
            #pragma unroll
            for (int ni = 0; ni < 4; ++ni)
                #pragma unroll
                for (int kk = 0; kk < 2; ++kk)
                    acc[mi][ni] = __builtin_amdgcn_mfma_f32_16x16x32_bf16(
                        af[mi][kk], bfr[ni][kk], acc[mi][ni], 0, 0, 0);
        __syncthreads();
    }

    // epilogue: D layout col=lane&15, row=(lane>>4)*4+reg  [m89]
    float* Ps = P + (size_t)kz * NB * NOUT;
    #pragma unroll
    for (int mi = 0; mi < 4; ++mi) {
        #pragma unroll
        for (int ni = 0; ni < 4; ++ni) {
            int row0 = m0 + wr * 64 + mi * 16 + fg * 4;
            int col  = n0 + wc * 64 + ni * 16 + fr;
            #pragma unroll
            for (int j = 0; j < 4; ++j)
                Ps[(size_t)(row0 + j) * NOUT + col] = acc[mi][ni][j];
        }
    }
}

// ---------------- reduce 4 partials + bias -> d_out ----
__global__ __launch_bounds__(256)
void k_reduce(const float4* __restrict__ P, const float4* __restrict__ bias4,
              float4* __restrict__ out) {
    int i = blockIdx.x * 256 + threadIdx.x;   // 0..262143 (float4 index)
    float4 a = P[i], b = P[i + 262144], c = P[i + 524288], d = P[i + 786432];
    float4 bb = bias4[i & 255];
    float4 r;
    r.x = a.x + b.x + c.x + d.x + bb.x;
    r.y = a.y + b.y + c.y + d.y + bb.y;
    r.z = a.z + b.z + c.z + d.z + bb.z;
    r.w = a.w + b.w + c.w + d.w + bb.w;
    out[i] = r;
}

// ---------------- launch ----------------
static inline size_t align256(size_t v) { return (v + 255) & ~(size_t)255; }

extern "C" void kernel_launch(void* const* d_in, const int* in_sizes, int n_in,
                              void* d_out, int out_size, void* d_ws, size_t ws_size,
                              hipStream_t stream) {
    const float* x    = (const float*)d_in[0];   // [NB][NIN]
    const float* wts  = (const float*)d_in[1];   // [NNZ]
    const float* bias = (const float*)d_in[2];   // [NOUT]
    const int*   idx  = (const int*)d_in[3];     // [2][NNZ] int32

    char* ws = (char*)d_ws;
    size_t off = 0;
    float* Wd = (float*)(ws + off); off = align256(off + (size_t)NOUT * NIN * 4);  // 4 MB
    bf16*  xb = (bf16*) (ws + off); off = align256(off + (size_t)NB * NIN * 2);    // 2 MB
    bf16*  wb = (bf16*) (ws + off); off = align256(off + (size_t)NOUT * NIN * 2);  // 2 MB
    float* P  = (float*)(ws + off); off = align256(off + (size_t)4 * NB * NOUT * 4); // 16 MB

    const int nb_nnz = (NNZ + 255) / 256;

    hipMemsetAsync(Wd, 0, (size_t)NOUT * NIN * 4, stream);
    k_densify<<<nb_nnz, 256, 0, stream>>>(idx, wts, Wd);
    k_convert<<<1024, 256, 0, stream>>>(x, Wd, xb, wb);
    k_gemm<<<dim3(8, 8, 4), 256, 0, stream>>>(xb, wb, P);
    k_reduce<<<1024, 256, 0, stream>>>((const float4*)P, (const float4*)bias,
                                       (float4*)d_out);
}

// Round 6
// 29.683 us; speedup vs baseline: 2.9591x; 1.1771x over previous
//
#include <hip/hip_runtime.h>
#include <hip/hip_bf16.h>

#define NNZ   104858
#define NB    1024
#define NIN   1024
#define NOUT  1024

typedef __bf16 bf16;
typedef bf16  bf16x8 __attribute__((ext_vector_type(8)));
typedef float f32x4  __attribute__((ext_vector_type(4)));

// ---------------- pre: zero Wd | convert x->bf16 ----------------
__global__ __launch_bounds__(256)
void k_pre(const float* __restrict__ x, float* __restrict__ Wd,
           bf16* __restrict__ xb) {
    const int b = blockIdx.x, t = threadIdx.x;
    if (b < 512) {
        float4 z = {0.f, 0.f, 0.f, 0.f};
        float4* w4 = (float4*)Wd;
        int i = (b * 256 + t) * 2;
        w4[i] = z; w4[i + 1] = z;
    } else {
        const int base = ((b - 512) * 256 + t) * 8;
        const float4* s4 = (const float4*)(x + base);
        float4 v0 = s4[0], v1 = s4[1];
        bf16x8 o;
        o[0] = (bf16)v0.x; o[1] = (bf16)v0.y; o[2] = (bf16)v0.z; o[3] = (bf16)v0.w;
        o[4] = (bf16)v1.x; o[5] = (bf16)v1.y; o[6] = (bf16)v1.z; o[7] = (bf16)v1.w;
        *(bf16x8*)(xb + base) = o;
    }
}

// ---------------- densify: Wd[r][c] += w_k (f32 atomics; duplicates sum) ----
__global__ __launch_bounds__(256)
void k_densify(const int* __restrict__ idx, const float* __restrict__ w,
               float* __restrict__ Wd) {
    int k = blockIdx.x * 256 + threadIdx.x;
    if (k < NNZ) {
        int r = idx[k] & (NOUT - 1);
        int c = idx[NNZ + k] & (NIN - 1);
        atomicAdd(&Wd[r * NIN + c], w[k]);
    }
}

// ---------------- convert W -> bf16 ----------------
__global__ __launch_bounds__(256)
void k_convW(const float* __restrict__ Wd, bf16* __restrict__ wb) {
    const int base = (blockIdx.x * 256 + threadIdx.x) * 8;
    const float4* s4 = (const float4*)(Wd + base);
    float4 v0 = s4[0], v1 = s4[1];
    bf16x8 o;
    o[0] = (bf16)v0.x; o[1] = (bf16)v0.y; o[2] = (bf16)v0.z; o[3] = (bf16)v0.w;
    o[4] = (bf16)v1.x; o[5] = (bf16)v1.y; o[6] = (bf16)v1.z; o[7] = (bf16)v1.w;
    *(bf16x8*)(wb + base) = o;
}

// ---------------- GEMM: out = x_bf16 * W_bf16^T + bias ----------------
// 64x64 tile, 512 threads (8 waves). Waves 0-3: K[0,512); waves 4-7: K[512,1024).
// Each half: 2x2 wave grid over the tile, own LDS buffers (round-5 verified
// staging/swizzle/MFMA structure). Cross-half reduce via LDS; single plain
// store to d_out (replay-stable: no RMW on d_out).
__device__ __forceinline__ void gload_lds16(const void* g, void* l) {
    __builtin_amdgcn_global_load_lds((const __attribute__((address_space(1))) void*)g,
                                     (__attribute__((address_space(3))) void*)l,
                                     16, 0, 0);
}

__global__ __launch_bounds__(512)
void k_gemm(const bf16* __restrict__ A, const bf16* __restrict__ B,
            const float* __restrict__ bias, float* __restrict__ out) {
    __shared__ __align__(16) bf16 As[2][64 * 64];   // [half]
    __shared__ __align__(16) bf16 Bs[2][64 * 64];
    __shared__ f32x4 red[4][64][4];                 // 16 KB reduce buffer

    const int t  = threadIdx.x;
    const int m0 = blockIdx.x * 64, n0 = blockIdx.y * 64;
    const int lane = t & 63;
    const int wv = t >> 6;              // 0..7
    const int half = wv >> 2;           // K split
    const int w4 = wv & 3, wr = w4 >> 1, wc = w4 & 1;
    const int fr = lane & 15, fg = lane >> 4;

    const int th   = t & 255;           // staging thread id within half
    const int srow = th >> 3;           // 0..31
    const int sg   = th & 7;            // 16B granule in 128B row

    f32x4 acc[2][2] = {};

    for (int ks = 0; ks < 8; ++ks) {
        const int kbase = half * 512 + ks * 64;
        #pragma unroll
        for (int i = 0; i < 2; ++i) {
            int row = i * 32 + srow;
            int g2  = sg ^ (row & 7);   // pre-swizzled source (rule #21)
            gload_lds16(A + (size_t)(m0 + row) * NIN + kbase + g2 * 8,
                        As[half] + row * 64 + sg * 8);
            gload_lds16(B + (size_t)(n0 + row) * NIN + kbase + g2 * 8,
                        Bs[half] + row * 64 + sg * 8);
        }
        __syncthreads();

        bf16x8 af[2][2], bfr[2][2];
        #pragma unroll
        for (int mi = 0; mi < 2; ++mi) {
            int row = wr * 32 + mi * 16 + fr;
            #pragma unroll
            for (int kk = 0; kk < 2; ++kk) {
                int gsw = (kk * 4 + fg) ^ (row & 7);
                af[mi][kk] = *(const bf16x8*)(As[half] + row * 64 + gsw * 8);
            }
        }
        #pragma unroll
        for (int ni = 0; ni < 2; ++ni) {
            int row = wc * 32 + ni * 16 + fr;
            #pragma unroll
            for (int kk = 0; kk < 2; ++kk) {
                int gsw = (kk * 4 + fg) ^ (row & 7);
                bfr[ni][kk] = *(const bf16x8*)(Bs[half] + row * 64 + gsw * 8);
            }
        }
        #pragma unroll
        for (int mi = 0; mi < 2; ++mi)
            #pragma unroll
            for (int ni = 0; ni < 2; ++ni)
                #pragma unroll
                for (int kk = 0; kk < 2; ++kk)
                    acc[mi][ni] = __builtin_amdgcn_mfma_f32_16x16x32_bf16(
                        af[mi][kk], bfr[ni][kk], acc[mi][ni], 0, 0, 0);
        __syncthreads();
    }

    // cross-half reduce: upper waves publish, lower waves combine + bias + store
    if (half == 1) {
        #pragma unroll
        for (int mi = 0; mi < 2; ++mi)
            #pragma unroll
            for (int ni = 0; ni < 2; ++ni)
                red[w4][lane][mi * 2 + ni] = acc[mi][ni];
    }
    __syncthreads();
    if (half == 0) {
        #pragma unroll
        for (int mi = 0; mi < 2; ++mi) {
            #pragma unroll
            for (int ni = 0; ni < 2; ++ni) {
                f32x4 p = red[w4][lane][mi * 2 + ni];
                int row0 = m0 + wr * 32 + mi * 16 + fg * 4;
                int col  = n0 + wc * 32 + ni * 16 + fr;
                float bb = bias[col];
                #pragma unroll
                for (int j = 0; j < 4; ++j)
                    out[(size_t)(row0 + j) * NOUT + col] = acc[mi][ni][j] + p[j] + bb;
            }
        }
    }
}

// ---------------- launch ----------------
static inline size_t align256(size_t v) { return (v + 255) & ~(size_t)255; }

extern "C" void kernel_launch(void* const* d_in, const int* in_sizes, int n_in,
                              void* d_out, int out_size, void* d_ws, size_t ws_size,
                              hipStream_t stream) {
    const float* x    = (const float*)d_in[0];   // [NB][NIN]
    const float* wts  = (const float*)d_in[1];   // [NNZ]
    const float* bias = (const float*)d_in[2];   // [NOUT]
    const int*   idx  = (const int*)d_in[3];     // [2][NNZ] int32

    char* ws = (char*)d_ws;
    size_t off = 0;
    float* Wd = (float*)(ws + off); off = align256(off + (size_t)NOUT * NIN * 4);  // 4 MB
    bf16*  xb = (bf16*) (ws + off); off = align256(off + (size_t)NB * NIN * 2);    // 2 MB
    bf16*  wb = (bf16*) (ws + off); off = align256(off + (size_t)NOUT * NIN * 2);  // 2 MB

    const int nb_nnz = (NNZ + 255) / 256;

    k_pre<<<1024, 256, 0, stream>>>(x, Wd, xb);
    k_densify<<<nb_nnz, 256, 0, stream>>>(idx, wts, Wd);
    k_convW<<<512, 256, 0, stream>>>(Wd, wb);
    k_gemm<<<dim3(16, 16), 512, 0, stream>>>(xb, wb, bias, (float*)d_out);
}

// Round 7
// 28.990 us; speedup vs baseline: 3.0299x; 1.0239x over previous
//
#include <hip/hip_runtime.h>
#include <hip/hip_bf16.h>

#define NNZ   104858
#define NB    1024
#define NIN   1024
#define NOUT  1024

typedef __bf16 bf16;
typedef bf16  bf16x8 __attribute__((ext_vector_type(8)));
typedef float f32x4  __attribute__((ext_vector_type(4)));

// ---------------- pre: zero Wd | convert x->bf16 ----------------
__global__ __launch_bounds__(256)
void k_pre(const float* __restrict__ x, float* __restrict__ Wd,
           bf16* __restrict__ xb) {
    const int b = blockIdx.x, t = threadIdx.x;
    if (b < 512) {
        float4 z = {0.f, 0.f, 0.f, 0.f};
        float4* w4 = (float4*)Wd;
        int i = (b * 256 + t) * 2;
        w4[i] = z; w4[i + 1] = z;
    } else {
        const int base = ((b - 512) * 256 + t) * 8;
        const float4* s4 = (const float4*)(x + base);
        float4 v0 = s4[0], v1 = s4[1];
        bf16x8 o;
        o[0] = (bf16)v0.x; o[1] = (bf16)v0.y; o[2] = (bf16)v0.z; o[3] = (bf16)v0.w;
        o[4] = (bf16)v1.x; o[5] = (bf16)v1.y; o[6] = (bf16)v1.z; o[7] = (bf16)v1.w;
        *(bf16x8*)(xb + base) = o;
    }
}

// ---------------- densify: Wd[r][c] += w_k (f32 atomics; duplicates sum) ----
__global__ __launch_bounds__(256)
void k_densify(const int* __restrict__ idx, const float* __restrict__ w,
               float* __restrict__ Wd) {
    int k = blockIdx.x * 256 + threadIdx.x;
    if (k < NNZ) {
        int r = idx[k] & (NOUT - 1);
        int c = idx[NNZ + k] & (NIN - 1);
        atomicAdd(&Wd[r * NIN + c], w[k]);
    }
}

// ---------------- GEMM: out = x_bf16 * bf16(Wd)^T + bias ----------------
// 64x64 tile, 512 threads (8 waves), in-block split-K=2 (round-6 verified core).
// A staged via global_load_lds from bf16 xb (pre-swizzled source);
// B reg-staged from f32 Wd with in-register f32->bf16 convert and write-side
// XOR-swizzled ds_write (same involution as read side). B-loads for ks+1 are
// issued after the staging barrier so they land under the MFMA phase (T14).
__device__ __forceinline__ void gload_lds16(const void* g, void* l) {
    __builtin_amdgcn_global_load_lds((const __attribute__((address_space(1))) void*)g,
                                     (__attribute__((address_space(3))) void*)l,
                                     16, 0, 0);
}

__global__ __launch_bounds__(512)
void k_gemm(const bf16* __restrict__ A, const float* __restrict__ Wd,
            const float* __restrict__ bias, float* __restrict__ out) {
    __shared__ __align__(16) bf16 As[2][64 * 64];   // [half]
    __shared__ __align__(16) bf16 Bs[2][64 * 64];
    __shared__ f32x4 red[4][64][4];                 // 16 KB reduce buffer

    // XCD-aware swizzle (T1): 256 blocks, 8 XCDs -> each XCD gets 32
    // consecutive swizzled ids = 2 full n-panels (512 KB Wd) + all xb (2 MB)
    const int b  = blockIdx.x;
    const int id = (b & 7) * 32 + (b >> 3);
    const int m0 = (id & 15) * 64, n0 = (id >> 4) * 64;

    const int t    = threadIdx.x;
    const int lane = t & 63;
    const int wv   = t >> 6;            // 0..7
    const int half = wv >> 2;           // K split
    const int w4   = wv & 3, wr = w4 >> 1, wc = w4 & 1;
    const int fr   = lane & 15, fg = lane >> 4;

    const int th   = t & 255;           // staging thread id within half
    const int srow = th >> 3;           // A: 0..31
    const int sg   = th & 7;            // A: 16B granule in 128B row
    const int brow = th >> 2;           // B: 0..63
    const int bq   = th & 3;            // B: 16-f32 quarter of the 64-col slice

    f32x4 acc[2][2] = {};

    // B reg preload for ks=0
    const float* wrow = Wd + (size_t)(n0 + brow) * NIN + half * 512;
    float4 bv0, bv1, bv2, bv3;
    {
        const float4* p = (const float4*)(wrow + bq * 16);
        bv0 = p[0]; bv1 = p[1]; bv2 = p[2]; bv3 = p[3];
    }

    for (int ks = 0; ks < 8; ++ks) {
        const int kbase = half * 512 + ks * 64;
        // stage A (async, LDS linear dest, pre-swizzled global source)
        #pragma unroll
        for (int i = 0; i < 2; ++i) {
            int row = i * 32 + srow;
            int g2  = sg ^ (row & 7);
            gload_lds16(A + (size_t)(m0 + row) * NIN + kbase + g2 * 8,
                        As[half] + row * 64 + sg * 8);
        }
        // stage B from regs: convert f32->bf16, swizzled ds_write
        {
            bf16x8 o0, o1;
            o0[0] = (bf16)bv0.x; o0[1] = (bf16)bv0.y; o0[2] = (bf16)bv0.z; o0[3] = (bf16)bv0.w;
            o0[4] = (bf16)bv1.x; o0[5] = (bf16)bv1.y; o0[6] = (bf16)bv1.z; o0[7] = (bf16)bv1.w;
            o1[0] = (bf16)bv2.x; o1[1] = (bf16)bv2.y; o1[2] = (bf16)bv2.z; o1[3] = (bf16)bv2.w;
            o1[4] = (bf16)bv3.x; o1[5] = (bf16)bv3.y; o1[6] = (bf16)bv3.z; o1[7] = (bf16)bv3.w;
            int g0 = (bq * 2)     ^ (brow & 7);
            int g1 = (bq * 2 + 1) ^ (brow & 7);
            *(bf16x8*)(Bs[half] + brow * 64 + g0 * 8) = o0;
            *(bf16x8*)(Bs[half] + brow * 64 + g1 * 8) = o1;
        }
        __syncthreads();

        // prefetch next B slice; lands under MFMA (drained by next barrier)
        if (ks < 7) {
            const float4* p = (const float4*)(wrow + (ks + 1) * 64 + bq * 16);
            bv0 = p[0]; bv1 = p[1]; bv2 = p[2]; bv3 = p[3];
        }

        bf16x8 af[2][2], bfr[2][2];
        #pragma unroll
        for (int mi = 0; mi < 2; ++mi) {
            int row = wr * 32 + mi * 16 + fr;
            #pragma unroll
            for (int kk = 0; kk < 2; ++kk) {
                int gsw = (kk * 4 + fg) ^ (row & 7);
                af[mi][kk] = *(const bf16x8*)(As[half] + row * 64 + gsw * 8);
            }
        }
        #pragma unroll
        for (int ni = 0; ni < 2; ++ni) {
            int row = wc * 32 + ni * 16 + fr;
            #pragma unroll
            for (int kk = 0; kk < 2; ++kk) {
                int gsw = (kk * 4 + fg) ^ (row & 7);
                bfr[ni][kk] = *(const bf16x8*)(Bs[half] + row * 64 + gsw * 8);
            }
        }
        #pragma unroll
        for (int mi = 0; mi < 2; ++mi)
            #pragma unroll
            for (int ni = 0; ni < 2; ++ni)
                #pragma unroll
                for (int kk = 0; kk < 2; ++kk)
                    acc[mi][ni] = __builtin_amdgcn_mfma_f32_16x16x32_bf16(
                        af[mi][kk], bfr[ni][kk], acc[mi][ni], 0, 0, 0);
        __syncthreads();
    }

    // cross-half reduce: upper waves publish, lower waves combine + bias + store
    if (half == 1) {
        #pragma unroll
        for (int mi = 0; mi < 2; ++mi)
            #pragma unroll
            for (int ni = 0; ni < 2; ++ni)
                red[w4][lane][mi * 2 + ni] = acc[mi][ni];
    }
    __syncthreads();
    if (half == 0) {
        #pragma unroll
        for (int mi = 0; mi < 2; ++mi) {
            #pragma unroll
            for (int ni = 0; ni < 2; ++ni) {
                f32x4 p = red[w4][lane][mi * 2 + ni];
                int row0 = m0 + wr * 32 + mi * 16 + fg * 4;
                int col  = n0 + wc * 32 + ni * 16 + fr;
                float bb = bias[col];
                #pragma unroll
                for (int j = 0; j < 4; ++j)
                    out[(size_t)(row0 + j) * NOUT + col] = acc[mi][ni][j] + p[j] + bb;
            }
        }
    }
}

// ---------------- launch ----------------
static inline size_t align256(size_t v) { return (v + 255) & ~(size_t)255; }

extern "C" void kernel_launch(void* const* d_in, const int* in_sizes, int n_in,
                              void* d_out, int out_size, void* d_ws, size_t ws_size,
                              hipStream_t stream) {
    const float* x    = (const float*)d_in[0];   // [NB][NIN]
    const float* wts  = (const float*)d_in[1];   // [NNZ]
    const float* bias = (const float*)d_in[2];   // [NOUT]
    const int*   idx  = (const int*)d_in[3];     // [2][NNZ] int32

    char* ws = (char*)d_ws;
    size_t off = 0;
    float* Wd = (float*)(ws + off); off = align256(off + (size_t)NOUT * NIN * 4);  // 4 MB
    bf16*  xb = (bf16*) (ws + off); off = align256(off + (size_t)NB * NIN * 2);    // 2 MB

    const int nb_nnz = (NNZ + 255) / 256;

    k_pre<<<1024, 256, 0, stream>>>(x, Wd, xb);
    k_densify<<<nb_nnz, 256, 0, stream>>>(idx, wts, Wd);
    k_gemm<<<256, 512, 0, stream>>>(xb, Wd, bias, (float*)d_out);
}